// Round 20
// baseline (40.095 us; speedup 1.0000x reference)
//
#include <hip/hip_runtime.h>
#include <cstdint>

// NT-Xent: B=4096, D=128, N=8192, T=0.5
// loss = mean_i( log(sum_{j!=i} exp(sim_ij/T)) - sim_{i,(i+B)%N}/T )
//
// R19 -> R20: revert phase-split (null). Single change on R18: MFMA shape
// 16x16x32 -> 32x32x16 (measured 17% higher rate: 2382 vs 2075 TF; half the
// MFMA instruction count, half the acc-init movs). C/D export uses the
// HW-verified mapping col=lane&31, row=(reg&3)+8*(reg>>2)+4*(lane>>5).
// Staging/vmcnt/swizzle/finalize identical to R18.

#define BROWS 4096
#define NROWS 8192
#define ROWB  256          // bytes per bf16 row
#define CSPL  24           // column splits: 32 rowblocks x 24 = 768 blocks
#define CT32  256          // 8192/32 column tiles (32-col)
#define BRT   256          // rows per block (4 waves x 64)
#define TILEB 8192         // bytes per 32-col B tile

typedef __attribute__((ext_vector_type(8)))  __bf16   bf16x8;
typedef __attribute__((ext_vector_type(16))) float    f32x16;
typedef __attribute__((ext_vector_type(4)))  uint32_t u32x4;

#define K1F 2.8853900817779268f   // (1/T)*log2(e)
#define LN2F 0.69314718055994531f
#define BC8(x) __builtin_bit_cast(bf16x8, x)

__device__ __forceinline__ uint16_t f2bf(float f) {
    uint32_t u = __builtin_bit_cast(uint32_t, f);
    u = (u + 0x7FFFu + ((u >> 16) & 1u)) >> 16;
    return (uint16_t)u;
}
__device__ __forceinline__ float bf2f(uint16_t b) {
    return __builtin_bit_cast(float, ((uint32_t)b) << 16);
}
__device__ __forceinline__ void gload_lds16(const void* g, void* l) {
    __builtin_amdgcn_global_load_lds(
        (const __attribute__((address_space(1))) void*)g,
        (__attribute__((address_space(3))) void*)l, 16, 0, 0);
}

// ---- kernel 1: L2-normalize rows; emit znB = bf16(x^), znA = bf16(K1*x^);
//      block 0 thread 0 also zeroes out[0]
__global__ __launch_bounds__(256) void k_normalize(
    const float* __restrict__ zi, const float* __restrict__ zj,
    uint16_t* __restrict__ znA, uint16_t* __restrict__ znB,
    float* __restrict__ out)
{
    if (blockIdx.x == 0 && threadIdx.x == 0) out[0] = 0.f;

    int tid  = threadIdx.x;
    int lane = tid & 63;
    int wid  = tid >> 6;
    int li   = lane & 7;
    int row  = blockIdx.x * 32 + wid * 8 + (lane >> 3);

    const float* src = (row < BROWS) ? (zi + (size_t)row * 128)
                                     : (zj + (size_t)(row - BROWS) * 128);
    float4 v[4];
    const float4* s4 = (const float4*)(src + li * 16);
#pragma unroll
    for (int c = 0; c < 4; ++c) v[c] = s4[c];

    float ss = 0.f;
#pragma unroll
    for (int c = 0; c < 4; ++c)
        ss += v[c].x*v[c].x + v[c].y*v[c].y + v[c].z*v[c].z + v[c].w*v[c].w;
#pragma unroll
    for (int off = 1; off < 8; off <<= 1) ss += __shfl_xor(ss, off);

    float scale = 1.0f / fmaxf(sqrtf(ss), 1e-8f);

    float e[16];
#pragma unroll
    for (int c = 0; c < 4; ++c) {
        e[c*4+0] = v[c].x * scale; e[c*4+1] = v[c].y * scale;
        e[c*4+2] = v[c].z * scale; e[c*4+3] = v[c].w * scale;
    }
    uint32_t wB[8], wA[8];
#pragma unroll
    for (int q = 0; q < 8; ++q) {
        wB[q] = (uint32_t)f2bf(e[2*q])       | ((uint32_t)f2bf(e[2*q+1])       << 16);
        wA[q] = (uint32_t)f2bf(e[2*q] * K1F) | ((uint32_t)f2bf(e[2*q+1] * K1F) << 16);
    }
    uint4* dB = (uint4*)((char*)znB + (size_t)row * ROWB + li * 32);
    dB[0] = make_uint4(wB[0], wB[1], wB[2], wB[3]);
    dB[1] = make_uint4(wB[4], wB[5], wB[6], wB[7]);
    uint4* dA = (uint4*)((char*)znA + (size_t)row * ROWB + li * 32);
    dA[0] = make_uint4(wA[0], wA[1], wA[2], wA[3]);
    dA[1] = make_uint4(wA[4], wA[5], wA[6], wA[7]);
}

// ---- kernel 2: 32x32x16-MFMA LDS-staged pipeline ----------------------------
// grid (32 rowblocks, 24 colsplits) = 768 blocks = 3/CU.
// Wave: 64 rows (2 row-tiles of 32) x 32-col tiles. A layout: row=lane&31,
// k-half=lane>>5. C/D: col=lane&31, row=(reg&3)+8*(reg>>2)+4*(lane>>5).
__global__ __launch_bounds__(256)
__attribute__((amdgpu_waves_per_eu(3, 3)))
void k_simlse(
    const uint16_t* __restrict__ znA, const uint16_t* __restrict__ znB,
    float* __restrict__ partial)
{
    __shared__ __align__(16) char lds[3][TILEB];

    const char* zA = (const char*)znA;
    const char* zB = (const char*)znB;
    int tid  = threadIdx.x;
    int lane = tid & 63;
    int wid  = tid >> 6;
    int lo32 = lane & 31;
    int half = lane >> 5;       // 0..1 (k-half)
    int rowBase = blockIdx.x * BRT + wid * 64;

    // A fragments (prescaled by K1): 2 row-tiles x 8 kf x 4 regs = 64 regs.
    u32x4 a[2][8];
#pragma unroll
    for (int rt = 0; rt < 2; ++rt) {
        const char* ap = zA + (size_t)(rowBase + rt * 32 + lo32) * ROWB + half * 16;
#pragma unroll
        for (int kf = 0; kf < 8; ++kf)
            a[rt][kf] = *(const u32x4*)(ap + kf * 32);
    }

    float rs[2][16];
#pragma unroll
    for (int rt = 0; rt < 2; ++rt)
#pragma unroll
        for (int r = 0; r < 16; ++r) rs[rt][r] = 0.f;

    int t0 = (CT32 * blockIdx.y) / CSPL;
    int t1 = (CT32 * (blockIdx.y + 1)) / CSPL;
    int nt = t1 - t0;

    const char* gsrc = zB + (size_t)t0 * TILEB
                     + ((tid * 16) ^ (((tid >> 4) & 7) << 4));
    int xorv = (lo32 & 7) << 4;        // read-side swizzle (row = lo32)

#define STAGE(sel, t) do {                                                     \
        const char* g_ = gsrc + (size_t)(t) * TILEB;                           \
        gload_lds16(g_,        &lds[sel][wid * 1024]);                         \
        gload_lds16(g_ + 4096, &lds[sel][4096 + wid * 1024]);                  \
    } while (0)

#define COMPUTE(sel) do {                                                        \
        const char* lb_ = &lds[sel][lo32 * 256];                                 \
        f32x16 ac0 = {0.f}, ac1 = {0.f};                                         \
        _Pragma("unroll")                                                        \
        for (int r = 0; r < 16; ++r) { ac0[r] = 0.f; ac1[r] = 0.f; }             \
        _Pragma("unroll")                                                        \
        for (int g = 0; g < 2; ++g) {                                            \
            u32x4 bf[4];                                                         \
            _Pragma("unroll")                                                    \
            for (int k = 0; k < 4; ++k)                                          \
                bf[k] = *(const u32x4*)(lb_ +                                    \
                            (((g * 4 + k) * 32 + half * 16) ^ xorv));            \
            _Pragma("unroll")                                                    \
            for (int k = 0; k < 4; ++k) {                                        \
                bf16x8 bk_ = BC8(bf[k]);                                         \
                ac0 = __builtin_amdgcn_mfma_f32_32x32x16_bf16(                   \
                          BC8(a[0][g * 4 + k]), bk_, ac0, 0, 0, 0);              \
                ac1 = __builtin_amdgcn_mfma_f32_32x32x16_bf16(                   \
                          BC8(a[1][g * 4 + k]), bk_, ac1, 0, 0, 0);              \
            }                                                                    \
        }                                                                        \
        _Pragma("unroll")                                                        \
        for (int r = 0; r < 16; ++r) {                                           \
            rs[0][r] += __builtin_amdgcn_exp2f(ac0[r]);                          \
            rs[1][r] += __builtin_amdgcn_exp2f(ac1[r]);                          \
        }                                                                        \
    } while (0)

    STAGE(0, 0);
    STAGE(1, 1);

    int t = 0;
    for (; t < nt - 1; ++t) {
        asm volatile("s_waitcnt vmcnt(2)" ::: "memory");
        __builtin_amdgcn_s_barrier();
        __builtin_amdgcn_sched_barrier(0);
        COMPUTE(t % 3);
        if (t + 2 < nt) STAGE((t + 2) % 3, t + 2);
    }
    asm volatile("s_waitcnt vmcnt(0)" ::: "memory");
    __builtin_amdgcn_s_barrier();
    __builtin_amdgcn_sched_barrier(0);
    COMPUTE(t % 3);

#undef STAGE
#undef COMPUTE

    // rowsum export: reduce across the 32 column-lanes (shfl_xor 1..16).
    // C/D row = (r&3) + 8*(r>>2) + 4*half; writers are lanes 0 and 32.
#pragma unroll
    for (int rt = 0; rt < 2; ++rt)
#pragma unroll
        for (int r = 0; r < 16; ++r) {
            float s = rs[rt][r];
            s += __shfl_xor(s, 1);  s += __shfl_xor(s, 2);
            s += __shfl_xor(s, 4);  s += __shfl_xor(s, 8);
            s += __shfl_xor(s, 16);
            if (lo32 == 0) {
                int row = rowBase + rt * 32 + (r & 3) + 8 * (r >> 2) + 4 * half;
                partial[blockIdx.y * NROWS + row] = s;
            }
        }
}

// ---- kernel 3: per-row lse - pos; 256 blocks, 8 lanes/row; atomic final ----
__global__ __launch_bounds__(256) void k_finalize(
    const uint16_t* __restrict__ znA, const uint16_t* __restrict__ znB,
    const float* __restrict__ partial, float* __restrict__ out)
{
    int tid = threadIdx.x;
    int r   = tid >> 3;                 // row within block, 0..31
    int sub = tid & 7;
    int i = blockIdx.x * 32 + r;

    float S = 0.f;
#pragma unroll
    for (int k = 0; k < 3; ++k) S += partial[(size_t)(sub + k * 8) * NROWS + i];

    int j = (i + BROWS) & (NROWS - 1);
    const uint4* rAi = (const uint4*)((const char*)znA + (size_t)i * ROWB);
    const uint4* rBi = (const uint4*)((const char*)znB + (size_t)i * ROWB);
    const uint4* rBj = (const uint4*)((const char*)znB + (size_t)j * ROWB);
    float adot = 0.f;   // K1 * <zn_i, zn_j>
    float sdot = 0.f;   // K1 * <zn_i, zn_i>
#pragma unroll
    for (int cc = 0; cc < 2; ++cc) {
        int c = sub * 2 + cc;
        uint4 ua = rAi[c], ub = rBi[c], vb = rBj[c];
        const uint32_t* pa = (const uint32_t*)&ua;
        const uint32_t* pb = (const uint32_t*)&ub;
        const uint32_t* pv = (const uint32_t*)&vb;
#pragma unroll
        for (int q = 0; q < 4; ++q) {
            float a0 = bf2f((uint16_t)(pa[q] & 0xffffu)), a1 = bf2f((uint16_t)(pa[q] >> 16));
            float b0 = bf2f((uint16_t)(pb[q] & 0xffffu)), b1 = bf2f((uint16_t)(pb[q] >> 16));
            float v0 = bf2f((uint16_t)(pv[q] & 0xffffu)), v1 = bf2f((uint16_t)(pv[q] >> 16));
            adot += a0 * v0 + a1 * v1;
            sdot += a0 * b0 + a1 * b1;
        }
    }
#pragma unroll
    for (int off = 1; off < 8; off <<= 1) {
        S    += __shfl_xor(S, off);
        adot += __shfl_xor(adot, off);
        sdot += __shfl_xor(sdot, off);
    }

    float c = 0.f;
    if (sub == 0) {
        S -= __builtin_amdgcn_exp2f(sdot);                 // remove diagonal
        c = LN2F * (__builtin_amdgcn_logf(S) - adot);      // ln(S) - pos/T
    }
#pragma unroll
    for (int off = 1; off < 64; off <<= 1) c += __shfl_xor(c, off);
    __shared__ float wsum[4];
    int lane = tid & 63, wid = tid >> 6;
    if (lane == 0) wsum[wid] = c;
    __syncthreads();
    if (tid == 0)
        atomicAdd(out, (wsum[0] + wsum[1] + wsum[2] + wsum[3])
                         * (1.0f / (float)NROWS));
}

extern "C" void kernel_launch(void* const* d_in, const int* in_sizes, int n_in,
                              void* d_out, int out_size, void* d_ws, size_t ws_size,
                              hipStream_t stream)
{
    const float* zi = (const float*)d_in[0];
    const float* zj = (const float*)d_in[1];
    float* out = (float*)d_out;

    char* ws = (char*)d_ws;
    uint16_t* znA      = (uint16_t*)ws;                                   // 2 MB
    uint16_t* znB      = (uint16_t*)(ws + (size_t)NROWS * ROWB);          // 2 MB
    float*    partial  = (float*)(ws + 2 * (size_t)NROWS * ROWB);         // 768 KB

    k_normalize<<<dim3(256), dim3(256), 0, stream>>>(zi, zj, znA, znB, out);
    k_simlse  <<<dim3(32, CSPL), dim3(256), 0, stream>>>(znA, znB, partial);
    k_finalize<<<dim3(256), dim3(256), 0, stream>>>(znA, znB, partial, out);
}

// Round 21
// 34.509 us; speedup vs baseline: 1.1619x; 1.1619x over previous
//
#include <hip/hip_runtime.h>
#include <cstdint>

// NT-Xent: B=4096, D=128, N=8192, T=0.5
// loss = mean_i( log(sum_{j!=i} exp(sim_ij/T)) - sim_{i,(i+B)%N}/T )
//
// R20 -> R21: revert 32x32 MFMA (regressed 40.1 vs 35.7 -- f32x16 acc
// pressure + 8-deep dependent chains). Restore the measured-best R16 config
// exactly: R9 k_simlse (16x16x32, ring-3, counted vmcnt), widened k_finalize
// (256 blocks, 8 lanes/row), separate k_reduce. 34.8us measured at R16.

#define BROWS 4096
#define NROWS 8192
#define ROWB  256          // bytes per bf16 row
#define CSPL  24           // column splits: 32 rowblocks x 24 = 768 blocks
#define CT32  256          // 8192/32 column tiles (32-col)
#define BRT   256          // rows per block (4 waves x 64)
#define TILEB 8192         // bytes per 32-col B tile

typedef __attribute__((ext_vector_type(8))) __bf16    bf16x8;
typedef __attribute__((ext_vector_type(4))) float     f32x4;
typedef __attribute__((ext_vector_type(4))) uint32_t  u32x4;

#define K1F 2.8853900817779268f   // (1/T)*log2(e)
#define LN2F 0.69314718055994531f
#define BC8(x) __builtin_bit_cast(bf16x8, x)

__device__ __forceinline__ uint16_t f2bf(float f) {
    uint32_t u = __builtin_bit_cast(uint32_t, f);
    u = (u + 0x7FFFu + ((u >> 16) & 1u)) >> 16;
    return (uint16_t)u;
}
__device__ __forceinline__ float bf2f(uint16_t b) {
    return __builtin_bit_cast(float, ((uint32_t)b) << 16);
}
__device__ __forceinline__ void gload_lds16(const void* g, void* l) {
    __builtin_amdgcn_global_load_lds(
        (const __attribute__((address_space(1))) void*)g,
        (__attribute__((address_space(3))) void*)l, 16, 0, 0);
}

// ---- kernel 1: L2-normalize rows; emit znB = bf16(x^), znA = bf16(K1*x^) ----
__global__ __launch_bounds__(256) void k_normalize(
    const float* __restrict__ zi, const float* __restrict__ zj,
    uint16_t* __restrict__ znA, uint16_t* __restrict__ znB)
{
    int tid  = threadIdx.x;
    int lane = tid & 63;
    int wid  = tid >> 6;
    int li   = lane & 7;
    int row  = blockIdx.x * 32 + wid * 8 + (lane >> 3);

    const float* src = (row < BROWS) ? (zi + (size_t)row * 128)
                                     : (zj + (size_t)(row - BROWS) * 128);
    float4 v[4];
    const float4* s4 = (const float4*)(src + li * 16);
#pragma unroll
    for (int c = 0; c < 4; ++c) v[c] = s4[c];

    float ss = 0.f;
#pragma unroll
    for (int c = 0; c < 4; ++c)
        ss += v[c].x*v[c].x + v[c].y*v[c].y + v[c].z*v[c].z + v[c].w*v[c].w;
#pragma unroll
    for (int off = 1; off < 8; off <<= 1) ss += __shfl_xor(ss, off);

    float scale = 1.0f / fmaxf(sqrtf(ss), 1e-8f);

    float e[16];
#pragma unroll
    for (int c = 0; c < 4; ++c) {
        e[c*4+0] = v[c].x * scale; e[c*4+1] = v[c].y * scale;
        e[c*4+2] = v[c].z * scale; e[c*4+3] = v[c].w * scale;
    }
    uint32_t wB[8], wA[8];
#pragma unroll
    for (int q = 0; q < 8; ++q) {
        wB[q] = (uint32_t)f2bf(e[2*q])       | ((uint32_t)f2bf(e[2*q+1])       << 16);
        wA[q] = (uint32_t)f2bf(e[2*q] * K1F) | ((uint32_t)f2bf(e[2*q+1] * K1F) << 16);
    }
    uint4* dB = (uint4*)((char*)znB + (size_t)row * ROWB + li * 32);
    dB[0] = make_uint4(wB[0], wB[1], wB[2], wB[3]);
    dB[1] = make_uint4(wB[4], wB[5], wB[6], wB[7]);
    uint4* dA = (uint4*)((char*)znA + (size_t)row * ROWB + li * 32);
    dA[0] = make_uint4(wA[0], wA[1], wA[2], wA[3]);
    dA[1] = make_uint4(wA[4], wA[5], wA[6], wA[7]);
}

// ---- kernel 2: R9/R16 pipeline (best known) ---------------------------------
__global__ __launch_bounds__(256)
__attribute__((amdgpu_waves_per_eu(3, 3)))
void k_simlse(
    const uint16_t* __restrict__ znA, const uint16_t* __restrict__ znB,
    float* __restrict__ partial)
{
    __shared__ __align__(16) char lds[3][TILEB];

    const char* zA = (const char*)znA;
    const char* zB = (const char*)znB;
    int tid  = threadIdx.x;
    int lane = tid & 63;
    int wid  = tid >> 6;
    int lo16 = lane & 15;
    int hi4  = lane >> 4;
    int rowBase = blockIdx.x * BRT + wid * 64;

    u32x4 a[4][4];
#pragma unroll
    for (int rt = 0; rt < 4; ++rt) {
        const char* ap = zA + (size_t)(rowBase + rt * 16 + lo16) * ROWB + hi4 * 16;
#pragma unroll
        for (int kf = 0; kf < 4; ++kf)
            a[rt][kf] = *(const u32x4*)(ap + kf * 64);
    }

    float rs[4][4];
#pragma unroll
    for (int rt = 0; rt < 4; ++rt)
#pragma unroll
        for (int r = 0; r < 4; ++r) rs[rt][r] = 0.f;

    int t0 = (CT32 * blockIdx.y) / CSPL;
    int t1 = (CT32 * (blockIdx.y + 1)) / CSPL;
    int nt = t1 - t0;

    const char* gsrc = zB + (size_t)t0 * TILEB
                     + ((tid * 16) ^ (((tid >> 4) & 7) << 4));
    int xorv = (lo16 & 7) << 4;

#define STAGE(sel, t) do {                                                     \
        const char* g_ = gsrc + (size_t)(t) * TILEB;                           \
        gload_lds16(g_,        &lds[sel][wid * 1024]);                         \
        gload_lds16(g_ + 4096, &lds[sel][4096 + wid * 1024]);                  \
    } while (0)

#define COMPUTE(sel) do {                                                        \
        _Pragma("unroll")                                                        \
        for (int ct = 0; ct < 2; ++ct) {                                         \
            const char* lb_ = &lds[sel][ct * 4096 + lo16 * 256];                 \
            u32x4 bf[4];                                                         \
            _Pragma("unroll")                                                    \
            for (int kf = 0; kf < 4; ++kf)                                       \
                bf[kf] = *(const u32x4*)(lb_ + ((hi4 * 16 + kf * 64) ^ xorv));   \
            f32x4 ac0 = {0.f,0.f,0.f,0.f}, ac1 = {0.f,0.f,0.f,0.f};              \
            f32x4 ac2 = {0.f,0.f,0.f,0.f}, ac3 = {0.f,0.f,0.f,0.f};              \
            _Pragma("unroll")                                                    \
            for (int kf = 0; kf < 4; ++kf) {                                     \
                bf16x8 bk_ = BC8(bf[kf]);                                        \
                ac0 = __builtin_amdgcn_mfma_f32_16x16x32_bf16(BC8(a[0][kf]), bk_, ac0, 0, 0, 0); \
                ac1 = __builtin_amdgcn_mfma_f32_16x16x32_bf16(BC8(a[1][kf]), bk_, ac1, 0, 0, 0); \
                ac2 = __builtin_amdgcn_mfma_f32_16x16x32_bf16(BC8(a[2][kf]), bk_, ac2, 0, 0, 0); \
                ac3 = __builtin_amdgcn_mfma_f32_16x16x32_bf16(BC8(a[3][kf]), bk_, ac3, 0, 0, 0); \
            }                                                                    \
            _Pragma("unroll")                                                    \
            for (int r = 0; r < 4; ++r) {                                        \
                rs[0][r] += __builtin_amdgcn_exp2f(ac0[r]);                      \
                rs[1][r] += __builtin_amdgcn_exp2f(ac1[r]);                      \
                rs[2][r] += __builtin_amdgcn_exp2f(ac2[r]);                      \
                rs[3][r] += __builtin_amdgcn_exp2f(ac3[r]);                      \
            }                                                                    \
        }                                                                        \
    } while (0)

    STAGE(0, 0);
    STAGE(1, 1);

    int t = 0;
    for (; t < nt - 1; ++t) {
        asm volatile("s_waitcnt vmcnt(2)" ::: "memory");
        __builtin_amdgcn_s_barrier();
        __builtin_amdgcn_sched_barrier(0);
        COMPUTE(t % 3);
        if (t + 2 < nt) STAGE((t + 2) % 3, t + 2);
    }
    asm volatile("s_waitcnt vmcnt(0)" ::: "memory");
    __builtin_amdgcn_s_barrier();
    __builtin_amdgcn_sched_barrier(0);
    COMPUTE(t % 3);

#undef STAGE
#undef COMPUTE

#pragma unroll
    for (int rt = 0; rt < 4; ++rt)
#pragma unroll
        for (int r = 0; r < 4; ++r) {
            float s = rs[rt][r];
            s += __shfl_xor(s, 1);  s += __shfl_xor(s, 2);
            s += __shfl_xor(s, 4);  s += __shfl_xor(s, 8);
            if (lo16 == 0) {
                int row = rowBase + rt * 16 + hi4 * 4 + r;
                partial[blockIdx.y * NROWS + row] = s;
            }
        }
}

// ---- kernel 3: per-row lse - pos; 256 blocks, 8 lanes per row ---------------
__global__ __launch_bounds__(256) void k_finalize(
    const uint16_t* __restrict__ znA, const uint16_t* __restrict__ znB,
    const float* __restrict__ partial, float* __restrict__ blocksum)
{
    int tid = threadIdx.x;
    int r   = tid >> 3;                 // row within block, 0..31
    int sub = tid & 7;
    int i = blockIdx.x * 32 + r;

    float S = 0.f;
#pragma unroll
    for (int k = 0; k < 3; ++k) S += partial[(size_t)(sub + k * 8) * NROWS + i];

    int j = (i + BROWS) & (NROWS - 1);
    const uint4* rAi = (const uint4*)((const char*)znA + (size_t)i * ROWB);
    const uint4* rBi = (const uint4*)((const char*)znB + (size_t)i * ROWB);
    const uint4* rBj = (const uint4*)((const char*)znB + (size_t)j * ROWB);
    float adot = 0.f;   // K1 * <zn_i, zn_j>
    float sdot = 0.f;   // K1 * <zn_i, zn_i>
#pragma unroll
    for (int cc = 0; cc < 2; ++cc) {
        int c = sub * 2 + cc;
        uint4 ua = rAi[c], ub = rBi[c], vb = rBj[c];
        const uint32_t* pa = (const uint32_t*)&ua;
        const uint32_t* pb = (const uint32_t*)&ub;
        const uint32_t* pv = (const uint32_t*)&vb;
#pragma unroll
        for (int q = 0; q < 4; ++q) {
            float a0 = bf2f((uint16_t)(pa[q] & 0xffffu)), a1 = bf2f((uint16_t)(pa[q] >> 16));
            float b0 = bf2f((uint16_t)(pb[q] & 0xffffu)), b1 = bf2f((uint16_t)(pb[q] >> 16));
            float v0 = bf2f((uint16_t)(pv[q] & 0xffffu)), v1 = bf2f((uint16_t)(pv[q] >> 16));
            adot += a0 * v0 + a1 * v1;
            sdot += a0 * b0 + a1 * b1;
        }
    }
#pragma unroll
    for (int off = 1; off < 8; off <<= 1) {
        S    += __shfl_xor(S, off);
        adot += __shfl_xor(adot, off);
        sdot += __shfl_xor(sdot, off);
    }

    float c = 0.f;
    if (sub == 0) {
        S -= __builtin_amdgcn_exp2f(sdot);                 // remove diagonal
        c = LN2F * (__builtin_amdgcn_logf(S) - adot);      // ln(S) - pos/T
    }
#pragma unroll
    for (int off = 1; off < 64; off <<= 1) c += __shfl_xor(c, off);
    __shared__ float wsum[4];
    int lane = tid & 63, wid = tid >> 6;
    if (lane == 0) wsum[wid] = c;
    __syncthreads();
    if (tid == 0) blocksum[blockIdx.x] = wsum[0] + wsum[1] + wsum[2] + wsum[3];
}

// ---- kernel 4: final scalar (256 blocksums) ---------------------------------
__global__ __launch_bounds__(64) void k_reduce(
    const float* __restrict__ blocksum, float* __restrict__ out)
{
    int tid = threadIdx.x;
    float v = 0.f;
#pragma unroll
    for (int k = 0; k < 4; ++k) v += blocksum[tid + k * 64];
#pragma unroll
    for (int off = 1; off < 64; off <<= 1) v += __shfl_xor(v, off);
    if (tid == 0) out[0] = v * (1.0f / (float)NROWS);
}

extern "C" void kernel_launch(void* const* d_in, const int* in_sizes, int n_in,
                              void* d_out, int out_size, void* d_ws, size_t ws_size,
                              hipStream_t stream)
{
    const float* zi = (const float*)d_in[0];
    const float* zj = (const float*)d_in[1];
    float* out = (float*)d_out;

    char* ws = (char*)d_ws;
    uint16_t* znA      = (uint16_t*)ws;                                   // 2 MB
    uint16_t* znB      = (uint16_t*)(ws + (size_t)NROWS * ROWB);          // 2 MB
    float*    partial  = (float*)(ws + 2 * (size_t)NROWS * ROWB);         // 768 KB
    float*    blocksum = (float*)(ws + 2 * (size_t)NROWS * ROWB
                                     + (size_t)CSPL * NROWS * 4);         // 1 KB

    k_normalize<<<dim3(256), dim3(256), 0, stream>>>(zi, zj, znA, znB);
    k_simlse  <<<dim3(32, CSPL), dim3(256), 0, stream>>>(znA, znB, partial);
    k_finalize<<<dim3(256), dim3(256), 0, stream>>>(znA, znB, partial, blocksum);
    k_reduce  <<<dim3(1), dim3(64), 0, stream>>>(blocksum, out);
}